// Round 4
// baseline (608.073 us; speedup 1.0000x reference)
//
#include <hip/hip_runtime.h>
#include <math.h>

#define B_ 16
#define C_ 129
#define T_ 2000
#define NF_ 40
#define ED_ 64
#define K_ 16
#define TP_ 500

// workspace float offsets
#define OFF_SB2 1040     // 40     folded sconv bias
#define OFF_PWC 1088     // 3200   pw weights * pbn scale
#define OFF_PB2 4288     // 80     folded pw bias
#define OFF_WP  4368     // 1280   wx0 @ proj_w  (16x80)
#define OFF_BP  5648     // 16     wx0 @ proj_b + b0
#define OFF_M0  5664     // 256    L0@L0.T - exp(ll0) I
#define OFF_M1  5920     // 256    L1@L1.T - exp(ll1) I
#define OFF_W1A 6224     // 768    tconv A-frag prepack (3 mt x 64 lanes x 8 bf16)
#define OFF_W2U 8192     // bf16 A-frag prepack of sconv weights: 396288 ushort
#define OFF_XP  1495040  // 16*500*16  per-step cell0 input projection (MFMA C-layout)
#define OFF_S2R 1623040  // 1.28M  raw sconv accumulator (atomicAdd target)

typedef __attribute__((ext_vector_type(8))) short s8v;
typedef __attribute__((ext_vector_type(4))) float f4v;
typedef __attribute__((ext_vector_type(4))) __fp16 h4v;
typedef __attribute__((ext_vector_type(2))) __fp16 h2v;

#define XROW 292         // xs row stride: 256 t + 24 halo + 12 left pad

__device__ __forceinline__ float elu_f(float x) {
    return x > 0.f ? x : (__expf(x) - 1.f);
}
// round-half-up fp32 -> bf16
__device__ __forceinline__ unsigned bfr(float v) {
    return (__float_as_uint(v) + 0x8000u) >> 16;
}

// ---- k3 helpers -----------------------------------------------------------

#define MFMA16(a, b, c) __builtin_amdgcn_mfma_f32_16x16x16f16(a, b, c, 0, 0, 0)

#define EXP2F(x) __builtin_amdgcn_exp2f(x)
#define RSQF(x) __builtin_amdgcn_rsqf(x)

// split a f32 quad into f16 hi + f16 residual lo (for split-precision MFMA)
__device__ __forceinline__ void split4(f4v v, h4v& hi, h4v& lo) {
    union UH { h4v h4; h2v h2[2]; } H, L;
    H.h2[0] = __builtin_amdgcn_cvt_pkrtz(v[0], v[1]);
    H.h2[1] = __builtin_amdgcn_cvt_pkrtz(v[2], v[3]);
    L.h2[0] = __builtin_amdgcn_cvt_pkrtz(v[0] - (float)H.h2[0][0],
                                         v[1] - (float)H.h2[0][1]);
    L.h2[1] = __builtin_amdgcn_cvt_pkrtz(v[2] - (float)H.h2[1][0],
                                         v[3] - (float)H.h2[1][1]);
    hi = H.h4;
    lo = L.h4;
}

// LayerNorm over the 16 rows of each batch-column + tanh, all in f32.
// Rows of column n live in 4 regs x lanes {n, n^16, n^32, n^48}: parallel
// butterfly via three INDEPENDENT shfl_xor (one bpermute latency, not two
// serial). G/Bb carry the 2*log2(e) fold so tanh(x) = 1 - 2/(exp2(a2)+1).
__device__ __forceinline__ f4v lnTanh(f4v pre, f4v G, f4v Bb) {
    float s1 = (pre[0] + pre[1]) + (pre[2] + pre[3]);
    float s2 = fmaf(pre[1], pre[1], pre[0] * pre[0]) +
               fmaf(pre[3], pre[3], pre[2] * pre[2]);
    const float s1a = __shfl_xor(s1, 16);
    const float s1b = __shfl_xor(s1, 32);
    const float s1c = __shfl_xor(s1, 48);
    const float s2a = __shfl_xor(s2, 16);
    const float s2b = __shfl_xor(s2, 32);
    const float s2c = __shfl_xor(s2, 48);
    s1 = (s1 + s1a) + (s1b + s1c);
    s2 = (s2 + s2a) + (s2b + s2c);
    const float mu = s1 * 0.0625f;
    const float inv = RSQF(fmaf(s2, 0.0625f, -mu * mu) + 1e-5f);
    f4v h;
#pragma unroll
    for (int j = 0; j < 4; ++j) {
        const float coef = inv * G[j];
        const float a2 = fmaf(pre[j], coef, fmaf(-mu, coef, Bb[j]));
        const float e2 = EXP2F(a2);
        h[j] = fmaf(-2.f, __builtin_amdgcn_rcpf(e2 + 1.f), 1.f);
    }
    return h;
}

struct P0 {
    const float *tconv_w, *tconv_b, *tbn_g, *tbn_b, *tbn_m, *tbn_v;
    const float *sconv_b, *sbn_g, *sbn_b, *sbn_m, *sbn_v;
    const float *pw_w, *pw_b, *pbn_g, *pbn_b, *pbn_m, *pbn_v;
    const float *proj_w, *proj_b, *wx0, *b0, *L0, *ll0, *L1, *ll1;
    const float *sconv_w;
    float* ws;
};

// Merged setup: blocks [0,1250) zero s2raw; [1250,1444) repack sconv bf16
// A-frags; [1444,1452) run the table setup (all regions disjoint).
__global__ __launch_bounds__(256) void k0_all(P0 p) {
    const int tid = threadIdx.x;
    float* ws = p.ws;
    const float eps = 1e-5f;

    if (blockIdx.x < 1250) {
        const int i = blockIdx.x * 256 + tid;
        if (i < 320000)
            ((float4*)(ws + OFF_S2R))[i] = make_float4(0.f, 0.f, 0.f, 0.f);
        return;
    }
    if (blockIdx.x < 1444) {
        const int e = (blockIdx.x - 1250) * 256 + tid;
        if (e >= C_ * 3 * 2 * 64) return;
        unsigned short* w2b = (unsigned short*)(ws + OFF_W2U);
        const int c = e / 384;
        int r = e - c * 384;
        const int mt = r >> 7; r &= 127;
        const int kc = r >> 6;
        const int lane = r & 63;
        const int g = mt * 16 + (lane & 15);
        const float sinv = (g < NF_) ? p.sbn_g[g] * rsqrtf(p.sbn_v[g] + 1e-5f) : 0.f;
        unsigned short o[8];
#pragma unroll
        for (int j = 0; j < 8; ++j) {
            const int f = kc * 32 + (lane >> 4) * 8 + j;
            float v = 0.f;
            if (g < NF_ && f < NF_) v = p.sconv_w[g * (NF_ * C_) + f * C_ + c] * sinv;
            o[j] = (unsigned short)bfr(v);
        }
        unsigned short* dst = w2b + (size_t)e * 8;
#pragma unroll
        for (int j = 0; j < 8; ++j) dst[j] = o[j];
        return;
    }

    const int gtid = (blockIdx.x - 1444) * 256 + tid;
    const int stride = 8 * 256;
    // tconv A-frag prepack (bf16): A[m=f][k=tap], K=32; tap 25 = folded bias
    for (int e = gtid; e < 192; e += stride) {
        const int mt = e >> 6, L = e & 63;
        const int f = mt * 16 + (L & 15);
        float inv = 0.f, bias = 0.f;
        if (f < NF_) {
            inv = p.tbn_g[f] / sqrtf(p.tbn_v[f] + eps);
            bias = p.tconv_b[f] * inv + p.tbn_b[f] - p.tbn_m[f] * inv;
        }
        unsigned short* dst = ((unsigned short*)(ws + OFF_W1A)) + e * 8;
#pragma unroll
        for (int j = 0; j < 8; ++j) {
            const int k = (L >> 4) * 8 + j;
            float v = 0.f;
            if (f < NF_) {
                if (k < 25) v = p.tconv_w[f * 25 + k] * inv;
                else if (k == 25) v = bias;
            }
            dst[j] = (unsigned short)bfr(v);
        }
    }
    for (int f = gtid; f < NF_; f += stride) {
        const float sinv = p.sbn_g[f] / sqrtf(p.sbn_v[f] + eps);
        ws[OFF_SB2 + f] = p.sconv_b[f] * sinv + p.sbn_b[f] - p.sbn_m[f] * sinv;
    }
    for (int e = gtid; e < 3200; e += stride) {
        const int g = e / 40;
        const float pinv = p.pbn_g[g] / sqrtf(p.pbn_v[g] + eps);
        ws[OFF_PWC + e] = p.pw_w[e] * pinv;
    }
    for (int g = gtid; g < 80; g += stride) {
        const float pinv = p.pbn_g[g] / sqrtf(p.pbn_v[g] + eps);
        ws[OFF_PB2 + g] = p.pw_b[g] * pinv + p.pbn_b[g] - p.pbn_m[g] * pinv;
    }
    for (int e = gtid; e < 1280; e += stride) {
        const int k = e / 80, g = e - k * 80;
        float a = 0.f;
        for (int ee = 0; ee < ED_; ++ee)
            a = fmaf(p.wx0[k * ED_ + ee], p.proj_w[ee * 80 + g], a);
        ws[OFF_WP + e] = a;
    }
    for (int k = gtid; k < K_; k += stride) {
        float a = p.b0[k];
        for (int ee = 0; ee < ED_; ++ee)
            a = fmaf(p.wx0[k * ED_ + ee], p.proj_b[ee], a);
        ws[OFF_BP + k] = a;
    }
    for (int e = gtid; e < 256; e += stride) {
        const int k = e >> 4, j = e & 15;
        float a0 = 0.f, a1 = 0.f;
        for (int i = 0; i < 16; ++i) {
            a0 = fmaf(p.L0[k * 16 + i], p.L0[j * 16 + i], a0);
            a1 = fmaf(p.L1[k * 16 + i], p.L1[j * 16 + i], a1);
        }
        if (k == j) { a0 -= expf(p.ll0[0]); a1 -= expf(p.ll1[0]); }
        ws[OFF_M0 + e] = a0;
        ws[OFF_M1 + e] = a1;
    }
}

// Both convs on MFMA (round-9 verified, unchanged).
__global__ __launch_bounds__(256, 4) void k1_mfma(
    const float* __restrict__ x, const unsigned short* __restrict__ w1a,
    const unsigned short* __restrict__ w2b, float* __restrict__ s2raw) {
    __shared__ float xs[17 * XROW];
    __shared__ unsigned int vsI[2048];      // 4 waves x 8 rows x 64 words

    const int tid = threadIdx.x;
    const int split = blockIdx.x & 7;
    const int tile = (blockIdx.x >> 3) & 7;
    const int b = blockIdx.x >> 6;
    const int c0 = (split * C_) >> 3;
    const int c1 = ((split + 1) * C_) >> 3;
    const int cc = c1 - c0;
    const int t0 = tile << 8;
    const int w = tid >> 6;
    const int lane = tid & 63;
    const int n = lane & 15;
    const int q = lane >> 4;
    const int qh = q >> 1;
    const int q1_2 = (q & 1) * 2;
    const bool q3 = (q == 3);
    const int wb = w << 9;
    const int w64 = w << 6;
    const int ln8 = n + q * 8;

    for (int i = tid; i < 2048; i += 256) vsI[i] = 0u;
    for (int e = tid; e < cc * XROW; e += 256) {
        const int cl = e / XROW;
        const int i = e - cl * XROW;
        const int t = t0 - 12 + i;
        float v = 0.f;
        if ((unsigned)t < (unsigned)T_) v = x[(b * C_ + c0 + cl) * T_ + t];
        xs[e] = v;
    }
    __syncthreads();

    const s8v* w1a8 = (const s8v*)w1a;
    s8v wA[3];
#pragma unroll
    for (int mt = 0; mt < 3; ++mt) wA[mt] = w1a8[mt * 64 + lane];

    f4v acc[4][3];
#pragma unroll
    for (int nt = 0; nt < 4; ++nt)
#pragma unroll
        for (int mt = 0; mt < 3; ++mt) acc[nt][mt] = (f4v)0.f;

    const s8v* w2b8 = (const s8v*)w2b;
    const f4v z4 = (f4v)0.f;

    for (int cl = 0; cl < cc; ++cl) {
        const int c = c0 + cl;
        s8v af[3][2];
#pragma unroll
        for (int mt = 0; mt < 3; ++mt)
#pragma unroll
            for (int kc = 0; kc < 2; ++kc)
                af[mt][kc] = w2b8[((c * 3 + mt) * 2 + kc) * 64 + lane];

        const float* xrow = &xs[cl * XROW + w64 + ln8];

#pragma unroll
        for (int nt = 0; nt < 4; ++nt) {
            float bx[8];
#pragma unroll
            for (int j = 0; j < 8; ++j) bx[j] = xrow[nt * 16 + j];
            if (q3) bx[1] = 1.0f;
            unsigned pw_[4];
#pragma unroll
            for (int jj = 0; jj < 4; ++jj)
                pw_[jj] = bfr(bx[2 * jj]) |
                    ((__float_as_uint(bx[2 * jj + 1]) + 0x8000u) & 0xFFFF0000u);
            const s8v bh = *(const s8v*)pw_;
#pragma unroll
            for (int mt = 0; mt < 3; ++mt) {
                const f4v vT = __builtin_amdgcn_mfma_f32_16x16x32_bf16(
                    wA[mt], bh, z4, 0, 0, 0);
                const float e0 = elu_f(vT[0]);
                const float e1 = elu_f(vT[1]);
                const float e2 = elu_f(vT[2]);
                const float e3 = elu_f(vT[3]);
                const unsigned lo = bfr(e0) |
                    ((__float_as_uint(e1) + 0x8000u) & 0xFFFF0000u);
                const unsigned hi = bfr(e2) |
                    ((__float_as_uint(e3) + 0x8000u) & 0xFFFF0000u);
                const int base = wb + ((2 * mt + qh) << 6) + (n << 2) + q1_2;
                vsI[base] = lo;
                vsI[base + 1] = hi;
            }
            __builtin_amdgcn_wave_barrier();
            const s8v b0 = *(const s8v*)&vsI[wb + (q << 6) + (n << 2)];
            const s8v b1 = *(const s8v*)&vsI[wb + ((4 + q) << 6) + (n << 2)];
#pragma unroll
            for (int mt = 0; mt < 3; ++mt) {
                acc[nt][mt] = __builtin_amdgcn_mfma_f32_16x16x32_bf16(
                    af[mt][0], b0, acc[nt][mt], 0, 0, 0);
                acc[nt][mt] = __builtin_amdgcn_mfma_f32_16x16x32_bf16(
                    af[mt][1], b1, acc[nt][mt], 0, 0, 0);
            }
            __builtin_amdgcn_wave_barrier();
        }
    }

#pragma unroll
    for (int nt = 0; nt < 4; ++nt) {
        const int t = t0 + w * 64 + nt * 16 + n;
        if (t >= T_) continue;
#pragma unroll
        for (int mt = 0; mt < 3; ++mt) {
#pragma unroll
            for (int r = 0; r < 4; ++r) {
                const int g = mt * 16 + q * 4 + r;
                if (g < NF_)
                    atomicAdd(&s2raw[(b * NF_ + g) * T_ + t], acc[nt][mt][r]);
            }
        }
    }
}

// Fused dw/pw/pool/proj (verified; xp stored in MFMA C-layout float4s:
// f4 index = t*64 + (k>>2)*16 + b, element j = k&3, so k3's lane l can
// load xp4[t*64 + l] directly).
__global__ __launch_bounds__(256) void k2_dwpw(
    const float* __restrict__ s2raw, const float* __restrict__ sb2,
    const float* __restrict__ dw_w, const float* __restrict__ dw_b,
    const float* __restrict__ pwc, const float* __restrict__ pb2,
    const float* __restrict__ WP, const float* __restrict__ bp,
    float* __restrict__ xp) {
    __shared__ float st[NF_ * 114];
    __shared__ float dwo[NF_ * 100];
    __shared__ float dwwl[NF_ * 15];
    __shared__ float dwbl[NF_];
    __shared__ float pwcl[80 * 40];
    __shared__ float pb2l[80];
    __shared__ float WPl[K_ * 80];
    __shared__ float bpl[K_];
    __shared__ float po[80 * 25];
    const int tid = threadIdx.x;
    const int b = blockIdx.x / 20;
    const int tp0 = (blockIdx.x % 20) * 25;
    const int tbase = tp0 * 4 - 7;
    for (int e = tid; e < NF_ * 114; e += 256) {
        const int f = e / 114;
        const int i = e - f * 114;
        const int t = tbase + i;
        float v = 0.f;
        if ((unsigned)t < (unsigned)T_)
            v = elu_f(s2raw[(b * NF_ + f) * T_ + t] + sb2[f]);
        st[e] = v;
    }
    for (int e = tid; e < 600; e += 256) dwwl[e] = dw_w[e];
    for (int e = tid; e < 3200; e += 256) pwcl[e] = pwc[e];
    for (int e = tid; e < 1280; e += 256) WPl[e] = WP[e];
    if (tid < NF_) dwbl[tid] = dw_b[tid];
    if (tid < 80) pb2l[tid] = pb2[tid];
    if (tid < K_) bpl[tid] = bp[tid];
    __syncthreads();
    for (int e = tid; e < 4000; e += 256) {
        const int f = e / 100;
        const int tq = e - f * 100;
        float a = dwbl[f];
#pragma unroll
        for (int kk = 0; kk < 15; ++kk)
            a = fmaf(dwwl[f * 15 + kk], st[f * 114 + tq + kk], a);
        dwo[e] = a;
    }
    __syncthreads();
    for (int e = tid; e < 2000; e += 256) {
        const int g = e / 25;
        const int tp = e - g * 25;
        float sum = 0.f;
#pragma unroll
        for (int dt = 0; dt < 4; ++dt) {
            float a = pb2l[g];
            for (int f = 0; f < NF_; ++f)
                a = fmaf(pwcl[g * 40 + f], dwo[f * 100 + tp * 4 + dt], a);
            sum += elu_f(a);
        }
        po[e] = sum * 0.25f;
    }
    __syncthreads();
    for (int e = tid; e < 400; e += 256) {
        const int tp = e >> 4;
        const int k = e & 15;
        float a = bpl[k];
        for (int g = 0; g < 80; ++g)
            a = fmaf(WPl[k * 80 + g], po[g * 25 + tp], a);
        // MFMA C-layout store: float idx = t*256 + (k>>2)*64 + b*4 + (k&3)
        xp[(tp0 + tp) * 256 + ((k & 12) << 4) + (b << 2) + (k & 3)] = a;
    }
}

// MFMA scan, SINGLE WAVE, zero synchronization. All 16 batches are the 16
// columns of v_mfma_f32_16x16x16f16; state lives in the C/D layout
// (col=batch=lane&15, row=(lane>>4)*4+reg), which for K=16 is IDENTICAL to
// the B-operand layout, so each cell's tanh output feeds the next MFMA
// in-register (validated: round-3 passed with absmax 0.0). Both cells run
// in ONE wave with cell1 lagged one step: per fused iteration, cell0
// computes h0_t (3 MFMAs) and cell1 computes h1_{t-1} (6 MFMAs) as two
// independent dependency chains the scheduler interleaves — no barriers,
// no LDS, no inter-wave handoff. Precision: f16 hi+lo split per operand
// (error ~1e-5/step); LN/tanh in exact f32.
__global__ __launch_bounds__(64, 1) void k3_scan(
    const float* __restrict__ xp, const float* __restrict__ M0,
    const float* __restrict__ M1, const float* __restrict__ wx1,
    const float* __restrict__ b1, const float* __restrict__ ln0_g,
    const float* __restrict__ ln0_b, const float* __restrict__ ln1_g,
    const float* __restrict__ ln1_b, float* __restrict__ out) {
    const int lane = threadIdx.x;
    const int n = lane & 15;         // batch column
    const int q = lane >> 4;         // row quadrant
    const int r0 = q << 2;           // first row of this lane's 4 regs
    const f4v z4 = (f4v)0.f;
    const float C2 = 2.8853900817779268f;   // 2*log2(e): folds tanh 2x + exp2

    // A-frags (row-major float4 per lane: A[m=lane&15][k=r0+j])
    h4v A0hi, A0lo, A1hi, A1lo, Whi, Wlo;
    { const f4v a = *(const f4v*)(M0 + n * 16 + r0);  split4(a, A0hi, A0lo); }
    { const f4v a = *(const f4v*)(M1 + n * 16 + r0);  split4(a, A1hi, A1lo); }
    { const f4v a = *(const f4v*)(wx1 + n * 16 + r0); split4(a, Whi, Wlo); }
    const f4v B1C = *(const f4v*)(b1 + r0);
    f4v G0, B0v, G1, B1v;
#pragma unroll
    for (int j = 0; j < 4; ++j) {
        G0[j] = C2 * ln0_g[r0 + j];  B0v[j] = C2 * ln0_b[r0 + j];
        G1[j] = C2 * ln1_g[r0 + j];  B1v[j] = C2 * ln1_b[r0 + j];
    }

    const f4v* xp4 = (const f4v*)xp;
    f4v Xb0 = xp4[lane];             // X_0 (lane l reads f4 #(t*64+l))
    f4v Xb1 = xp4[64 + lane];        // X_1

    h4v S0hi, S0lo, S1hi{}, S1lo{};  // h0 / h1 state frags (h1 starts 0)

    // t = 0 peel: h0_0 = tanh(LN(X_0))  (h0_{-1} = 0 so pre0 = X_0 exactly)
    {
        const f4v h0 = lnTanh(Xb0, G0, B0v);
        split4(h0, S0hi, S0lo);
        Xb0 = Xb1;
        Xb1 = xp4[2 * 64 + lane];
    }

    // fused iters t = 1..499: cell0 -> h0_t ; cell1 -> h1_{t-1}
    for (int t = 1; t < TP_; ++t) {
        const h4v P0hi = S0hi, P0lo = S0lo;   // h0_{t-1} for cell1
        const f4v Xc = Xb0;
        Xb0 = Xb1;
        const int tn = (t + 2 < TP_) ? t + 2 : TP_ - 1;
        Xb1 = xp4[tn * 64 + lane];

        // cell0: M0*h0_{t-1} + X_t   (3 MFMAs, chains depth <= 2)
        f4v c1 = MFMA16(A0hi, S0hi, Xc);
        f4v c2 = MFMA16(A0hi, S0lo, z4);
        c2 = MFMA16(A0lo, S0hi, c2);
        // cell1: wx1*h0_{t-1} + M1*h1_{t-2} + b1   (6 MFMAs, 3 chains)
        f4v d1 = MFMA16(Whi, P0hi, B1C);
        d1 = MFMA16(A1hi, S1hi, d1);
        f4v d2 = MFMA16(Wlo, P0hi, z4);
        d2 = MFMA16(A1hi, S1lo, d2);
        f4v d3 = MFMA16(Whi, P0lo, z4);
        d3 = MFMA16(A1lo, S1hi, d3);

        const f4v pre0 = c1 + c2;
        const f4v pre1 = (d1 + d2) + d3;
        const f4v h0 = lnTanh(pre0, G0, B0v);
        const f4v h1 = lnTanh(pre1, G1, B1v);
        split4(h0, S0hi, S0lo);
        split4(h1, S1hi, S1lo);
    }

    // final peel: h1_499 from h0_499 (= current S0) and h1_498 (= S1)
    f4v hlast;
    {
        f4v d1 = MFMA16(Whi, S0hi, B1C);
        d1 = MFMA16(A1hi, S1hi, d1);
        f4v d2 = MFMA16(Wlo, S0hi, z4);
        d2 = MFMA16(A1hi, S1lo, d2);
        f4v d3 = MFMA16(Whi, S0lo, z4);
        d3 = MFMA16(A1lo, S1hi, d3);
        hlast = lnTanh((d1 + d2) + d3, G1, B1v);
    }

    // Z = h1_499: lane (q,n) holds rows r0..r0+3 of batch n -> float4
    *(f4v*)(out + n * K_ + r0) = hlast;
    if (q == 0) out[256 + n] = 1.0f;   // alpha = softmax over size-1 axis
}

extern "C" void kernel_launch(void* const* d_in, const int* in_sizes, int n_in,
                              void* d_out, int out_size, void* d_ws, size_t ws_size,
                              hipStream_t stream) {
    const float* x       = (const float*)d_in[0];
    const float* dw_w    = (const float*)d_in[13];
    const float* dw_b    = (const float*)d_in[14];
    const float* wx1     = (const float*)d_in[29];
    const float* b1      = (const float*)d_in[32];
    const float* ln0_g   = (const float*)d_in[27];
    const float* ln0_b   = (const float*)d_in[28];
    const float* ln1_g   = (const float*)d_in[33];
    const float* ln1_b   = (const float*)d_in[34];
    float* ws = (float*)d_ws;
    float* out = (float*)d_out;

    P0 p;
    p.tconv_w = (const float*)d_in[1]; p.tconv_b = (const float*)d_in[2];
    p.tbn_g = (const float*)d_in[3]; p.tbn_b = (const float*)d_in[4];
    p.tbn_m = (const float*)d_in[5]; p.tbn_v = (const float*)d_in[6];
    p.sconv_b = (const float*)d_in[8];
    p.sbn_g = (const float*)d_in[9]; p.sbn_b = (const float*)d_in[10];
    p.sbn_m = (const float*)d_in[11]; p.sbn_v = (const float*)d_in[12];
    p.pw_w = (const float*)d_in[15]; p.pw_b = (const float*)d_in[16];
    p.pbn_g = (const float*)d_in[17]; p.pbn_b = (const float*)d_in[18];
    p.pbn_m = (const float*)d_in[19]; p.pbn_v = (const float*)d_in[20];
    p.proj_w = (const float*)d_in[21]; p.proj_b = (const float*)d_in[22];
    p.wx0 = (const float*)d_in[23]; p.b0 = (const float*)d_in[26];
    p.L0 = (const float*)d_in[24]; p.ll0 = (const float*)d_in[25];
    p.L1 = (const float*)d_in[30]; p.ll1 = (const float*)d_in[31];
    p.sconv_w = (const float*)d_in[7];
    p.ws = ws;

    unsigned short* w2b = (unsigned short*)(ws + OFF_W2U);
    unsigned short* w1a = (unsigned short*)(ws + OFF_W1A);

    k0_all<<<dim3(1452), dim3(256), 0, stream>>>(p);
    k1_mfma<<<dim3(1024), dim3(256), 0, stream>>>(x, w1a, w2b, ws + OFF_S2R);
    k2_dwpw<<<dim3(320), dim3(256), 0, stream>>>(ws + OFF_S2R, ws + OFF_SB2,
                                                 dw_w, dw_b, ws + OFF_PWC,
                                                 ws + OFF_PB2, ws + OFF_WP, ws + OFF_BP,
                                                 ws + OFF_XP);
    k3_scan<<<dim3(1), dim3(64), 0, stream>>>(ws + OFF_XP, ws + OFF_M0, ws + OFF_M1,
                                              wx1, b1, ln0_g, ln0_b, ln1_g, ln1_b, out);
}

// Round 6
// 369.796 us; speedup vs baseline: 1.6443x; 1.6443x over previous
//
#include <hip/hip_runtime.h>
#include <math.h>

#define B_ 16
#define C_ 129
#define T_ 2000
#define NF_ 40
#define ED_ 64
#define K_ 16
#define TP_ 500

// workspace float offsets
#define OFF_SB2 1040     // 40     folded sconv bias
#define OFF_PWC 1088     // 3200   pw weights * pbn scale
#define OFF_PB2 4288     // 80     folded pw bias
#define OFF_WP  4368     // 1280   wx0 @ proj_w  (16x80)
#define OFF_BP  5648     // 16     wx0 @ proj_b + b0
#define OFF_M0  5664     // 256    L0@L0.T - exp(ll0) I
#define OFF_M1  5920     // 256    L1@L1.T - exp(ll1) I
#define OFF_W1A 6224     // 768    tconv A-frag prepack (3 mt x 64 lanes x 8 bf16)
#define OFF_W2U 8192     // bf16 A-frag prepack of sconv weights: 396288 ushort
#define OFF_XP  1495040  // 16*500*16  per-step cell0 input projection
#define OFF_S2R 1623040  // 1.28M  raw sconv accumulator (atomicAdd target)

typedef __attribute__((ext_vector_type(8))) short s8v;
typedef __attribute__((ext_vector_type(4))) float f4v;

#define XROW 292         // xs row stride: 256 t + 24 halo + 12 left pad

__device__ __forceinline__ float elu_f(float x) {
    return x > 0.f ? x : (__expf(x) - 1.f);
}
// tanh(x) given a2 = 2*log2(e)*x: 1 - 2*rcp(exp2(a2)+1); saturates at +-inf.
// (exp2 direct: the 2*log2e fold lives in the LN gain/bias constants.)
__device__ __forceinline__ float tanh2e_f(float a2) {
    return fmaf(-2.f,
                __builtin_amdgcn_rcpf(__builtin_amdgcn_exp2f(a2) + 1.f), 1.f);
}
// round-half-up fp32 -> bf16
__device__ __forceinline__ unsigned bfr(float v) {
    return (__float_as_uint(v) + 0x8000u) >> 16;
}

// DPP helpers: row_ror:n ctrl = 0x120+n, rows of 16 lanes.
#define DPPF(v, ctrl) __int_as_float(__builtin_amdgcn_update_dpp( \
    0, __float_as_int(v), (ctrl), 0xF, 0xF, false))

#define RSUM16(s) do {                     \
    s += DPPF(s, 0x128);                   \
    s += DPPF(s, 0x124);                   \
    s += DPPF(s, 0x122);                   \
    s += DPPF(s, 0x121);                   \
} while (0)

// wave-uniform broadcast of lane L's value (SGPR result)
#define RDLANE(v, L) __int_as_float(__builtin_amdgcn_readlane(__float_as_int(v), (L)))

#define C2F 2.8853900817779268f   // 2*log2(e)

struct P0 {
    const float *tconv_w, *tconv_b, *tbn_g, *tbn_b, *tbn_m, *tbn_v;
    const float *sconv_b, *sbn_g, *sbn_b, *sbn_m, *sbn_v;
    const float *pw_w, *pw_b, *pbn_g, *pbn_b, *pbn_m, *pbn_v;
    const float *proj_w, *proj_b, *wx0, *b0, *L0, *ll0, *L1, *ll1;
    const float *sconv_w;
    float* ws;
};

// Merged setup: blocks [0,1250) zero s2raw; [1250,1444) repack sconv bf16
// A-frags; [1444,1452) run the table setup (all regions disjoint).
__global__ __launch_bounds__(256) void k0_all(P0 p) {
    const int tid = threadIdx.x;
    float* ws = p.ws;
    const float eps = 1e-5f;

    if (blockIdx.x < 1250) {
        const int i = blockIdx.x * 256 + tid;
        if (i < 320000)
            ((float4*)(ws + OFF_S2R))[i] = make_float4(0.f, 0.f, 0.f, 0.f);
        return;
    }
    if (blockIdx.x < 1444) {
        const int e = (blockIdx.x - 1250) * 256 + tid;
        if (e >= C_ * 3 * 2 * 64) return;
        unsigned short* w2b = (unsigned short*)(ws + OFF_W2U);
        const int c = e / 384;
        int r = e - c * 384;
        const int mt = r >> 7; r &= 127;
        const int kc = r >> 6;
        const int lane = r & 63;
        const int g = mt * 16 + (lane & 15);
        const float sinv = (g < NF_) ? p.sbn_g[g] * rsqrtf(p.sbn_v[g] + 1e-5f) : 0.f;
        unsigned short o[8];
#pragma unroll
        for (int j = 0; j < 8; ++j) {
            const int f = kc * 32 + (lane >> 4) * 8 + j;
            float v = 0.f;
            if (g < NF_ && f < NF_) v = p.sconv_w[g * (NF_ * C_) + f * C_ + c] * sinv;
            o[j] = (unsigned short)bfr(v);
        }
        unsigned short* dst = w2b + (size_t)e * 8;
#pragma unroll
        for (int j = 0; j < 8; ++j) dst[j] = o[j];
        return;
    }

    const int gtid = (blockIdx.x - 1444) * 256 + tid;
    const int stride = 8 * 256;
    // tconv A-frag prepack (bf16): A[m=f][k=tap], K=32; tap 25 = folded bias
    for (int e = gtid; e < 192; e += stride) {
        const int mt = e >> 6, L = e & 63;
        const int f = mt * 16 + (L & 15);
        float inv = 0.f, bias = 0.f;
        if (f < NF_) {
            inv = p.tbn_g[f] / sqrtf(p.tbn_v[f] + eps);
            bias = p.tconv_b[f] * inv + p.tbn_b[f] - p.tbn_m[f] * inv;
        }
        unsigned short* dst = ((unsigned short*)(ws + OFF_W1A)) + e * 8;
#pragma unroll
        for (int j = 0; j < 8; ++j) {
            const int k = (L >> 4) * 8 + j;
            float v = 0.f;
            if (f < NF_) {
                if (k < 25) v = p.tconv_w[f * 25 + k] * inv;
                else if (k == 25) v = bias;
            }
            dst[j] = (unsigned short)bfr(v);
        }
    }
    for (int f = gtid; f < NF_; f += stride) {
        const float sinv = p.sbn_g[f] / sqrtf(p.sbn_v[f] + eps);
        ws[OFF_SB2 + f] = p.sconv_b[f] * sinv + p.sbn_b[f] - p.sbn_m[f] * sinv;
    }
    for (int e = gtid; e < 3200; e += stride) {
        const int g = e / 40;
        const float pinv = p.pbn_g[g] / sqrtf(p.pbn_v[g] + eps);
        ws[OFF_PWC + e] = p.pw_w[e] * pinv;
    }
    for (int g = gtid; g < 80; g += stride) {
        const float pinv = p.pbn_g[g] / sqrtf(p.pbn_v[g] + eps);
        ws[OFF_PB2 + g] = p.pw_b[g] * pinv + p.pbn_b[g] - p.pbn_m[g] * pinv;
    }
    for (int e = gtid; e < 1280; e += stride) {
        const int k = e / 80, g = e - k * 80;
        float a = 0.f;
        for (int ee = 0; ee < ED_; ++ee)
            a = fmaf(p.wx0[k * ED_ + ee], p.proj_w[ee * 80 + g], a);
        ws[OFF_WP + e] = a;
    }
    for (int k = gtid; k < K_; k += stride) {
        float a = p.b0[k];
        for (int ee = 0; ee < ED_; ++ee)
            a = fmaf(p.wx0[k * ED_ + ee], p.proj_b[ee], a);
        ws[OFF_BP + k] = a;
    }
    for (int e = gtid; e < 256; e += stride) {
        const int k = e >> 4, j = e & 15;
        float a0 = 0.f, a1 = 0.f;
        for (int i = 0; i < 16; ++i) {
            a0 = fmaf(p.L0[k * 16 + i], p.L0[j * 16 + i], a0);
            a1 = fmaf(p.L1[k * 16 + i], p.L1[j * 16 + i], a1);
        }
        if (k == j) { a0 -= expf(p.ll0[0]); a1 -= expf(p.ll1[0]); }
        ws[OFF_M0 + e] = a0;
        ws[OFF_M1 + e] = a1;
    }
}

// Both convs on MFMA (round-9 verified, unchanged).
__global__ __launch_bounds__(256, 4) void k1_mfma(
    const float* __restrict__ x, const unsigned short* __restrict__ w1a,
    const unsigned short* __restrict__ w2b, float* __restrict__ s2raw) {
    __shared__ float xs[17 * XROW];
    __shared__ unsigned int vsI[2048];      // 4 waves x 8 rows x 64 words

    const int tid = threadIdx.x;
    const int split = blockIdx.x & 7;
    const int tile = (blockIdx.x >> 3) & 7;
    const int b = blockIdx.x >> 6;
    const int c0 = (split * C_) >> 3;
    const int c1 = ((split + 1) * C_) >> 3;
    const int cc = c1 - c0;
    const int t0 = tile << 8;
    const int w = tid >> 6;
    const int lane = tid & 63;
    const int n = lane & 15;
    const int q = lane >> 4;
    const int qh = q >> 1;
    const int q1_2 = (q & 1) * 2;
    const bool q3 = (q == 3);
    const int wb = w << 9;
    const int w64 = w << 6;
    const int ln8 = n + q * 8;

    for (int i = tid; i < 2048; i += 256) vsI[i] = 0u;
    for (int e = tid; e < cc * XROW; e += 256) {
        const int cl = e / XROW;
        const int i = e - cl * XROW;
        const int t = t0 - 12 + i;
        float v = 0.f;
        if ((unsigned)t < (unsigned)T_) v = x[(b * C_ + c0 + cl) * T_ + t];
        xs[e] = v;
    }
    __syncthreads();

    const s8v* w1a8 = (const s8v*)w1a;
    s8v wA[3];
#pragma unroll
    for (int mt = 0; mt < 3; ++mt) wA[mt] = w1a8[mt * 64 + lane];

    f4v acc[4][3];
#pragma unroll
    for (int nt = 0; nt < 4; ++nt)
#pragma unroll
        for (int mt = 0; mt < 3; ++mt) acc[nt][mt] = (f4v)0.f;

    const s8v* w2b8 = (const s8v*)w2b;
    const f4v z4 = (f4v)0.f;

    for (int cl = 0; cl < cc; ++cl) {
        const int c = c0 + cl;
        s8v af[3][2];
#pragma unroll
        for (int mt = 0; mt < 3; ++mt)
#pragma unroll
            for (int kc = 0; kc < 2; ++kc)
                af[mt][kc] = w2b8[((c * 3 + mt) * 2 + kc) * 64 + lane];

        const float* xrow = &xs[cl * XROW + w64 + ln8];

#pragma unroll
        for (int nt = 0; nt < 4; ++nt) {
            float bx[8];
#pragma unroll
            for (int j = 0; j < 8; ++j) bx[j] = xrow[nt * 16 + j];
            if (q3) bx[1] = 1.0f;
            unsigned pw_[4];
#pragma unroll
            for (int jj = 0; jj < 4; ++jj)
                pw_[jj] = bfr(bx[2 * jj]) |
                    ((__float_as_uint(bx[2 * jj + 1]) + 0x8000u) & 0xFFFF0000u);
            const s8v bh = *(const s8v*)pw_;
#pragma unroll
            for (int mt = 0; mt < 3; ++mt) {
                const f4v vT = __builtin_amdgcn_mfma_f32_16x16x32_bf16(
                    wA[mt], bh, z4, 0, 0, 0);
                const float e0 = elu_f(vT[0]);
                const float e1 = elu_f(vT[1]);
                const float e2 = elu_f(vT[2]);
                const float e3 = elu_f(vT[3]);
                const unsigned lo = bfr(e0) |
                    ((__float_as_uint(e1) + 0x8000u) & 0xFFFF0000u);
                const unsigned hi = bfr(e2) |
                    ((__float_as_uint(e3) + 0x8000u) & 0xFFFF0000u);
                const int base = wb + ((2 * mt + qh) << 6) + (n << 2) + q1_2;
                vsI[base] = lo;
                vsI[base + 1] = hi;
            }
            __builtin_amdgcn_wave_barrier();
            const s8v b0 = *(const s8v*)&vsI[wb + (q << 6) + (n << 2)];
            const s8v b1 = *(const s8v*)&vsI[wb + ((4 + q) << 6) + (n << 2)];
#pragma unroll
            for (int mt = 0; mt < 3; ++mt) {
                acc[nt][mt] = __builtin_amdgcn_mfma_f32_16x16x32_bf16(
                    af[mt][0], b0, acc[nt][mt], 0, 0, 0);
                acc[nt][mt] = __builtin_amdgcn_mfma_f32_16x16x32_bf16(
                    af[mt][1], b1, acc[nt][mt], 0, 0, 0);
            }
            __builtin_amdgcn_wave_barrier();
        }
    }

#pragma unroll
    for (int nt = 0; nt < 4; ++nt) {
        const int t = t0 + w * 64 + nt * 16 + n;
        if (t >= T_) continue;
#pragma unroll
        for (int mt = 0; mt < 3; ++mt) {
#pragma unroll
            for (int r = 0; r < 4; ++r) {
                const int g = mt * 16 + q * 4 + r;
                if (g < NF_)
                    atomicAdd(&s2raw[(b * NF_ + g) * T_ + t], acc[nt][mt][r]);
            }
        }
    }
}

// Fused dw/pw/pool/proj (round-0 verified, xp row-major store restored).
__global__ __launch_bounds__(256) void k2_dwpw(
    const float* __restrict__ s2raw, const float* __restrict__ sb2,
    const float* __restrict__ dw_w, const float* __restrict__ dw_b,
    const float* __restrict__ pwc, const float* __restrict__ pb2,
    const float* __restrict__ WP, const float* __restrict__ bp,
    float* __restrict__ xp) {
    __shared__ float st[NF_ * 114];
    __shared__ float dwo[NF_ * 100];
    __shared__ float dwwl[NF_ * 15];
    __shared__ float dwbl[NF_];
    __shared__ float pwcl[80 * 40];
    __shared__ float pb2l[80];
    __shared__ float WPl[K_ * 80];
    __shared__ float bpl[K_];
    __shared__ float po[80 * 25];
    const int tid = threadIdx.x;
    const int b = blockIdx.x / 20;
    const int tp0 = (blockIdx.x % 20) * 25;
    const int tbase = tp0 * 4 - 7;
    for (int e = tid; e < NF_ * 114; e += 256) {
        const int f = e / 114;
        const int i = e - f * 114;
        const int t = tbase + i;
        float v = 0.f;
        if ((unsigned)t < (unsigned)T_)
            v = elu_f(s2raw[(b * NF_ + f) * T_ + t] + sb2[f]);
        st[e] = v;
    }
    for (int e = tid; e < 600; e += 256) dwwl[e] = dw_w[e];
    for (int e = tid; e < 3200; e += 256) pwcl[e] = pwc[e];
    for (int e = tid; e < 1280; e += 256) WPl[e] = WP[e];
    if (tid < NF_) dwbl[tid] = dw_b[tid];
    if (tid < 80) pb2l[tid] = pb2[tid];
    if (tid < K_) bpl[tid] = bp[tid];
    __syncthreads();
    for (int e = tid; e < 4000; e += 256) {
        const int f = e / 100;
        const int tq = e - f * 100;
        float a = dwbl[f];
#pragma unroll
        for (int kk = 0; kk < 15; ++kk)
            a = fmaf(dwwl[f * 15 + kk], st[f * 114 + tq + kk], a);
        dwo[e] = a;
    }
    __syncthreads();
    for (int e = tid; e < 2000; e += 256) {
        const int g = e / 25;
        const int tp = e - g * 25;
        float sum = 0.f;
#pragma unroll
        for (int dt = 0; dt < 4; ++dt) {
            float a = pb2l[g];
            for (int f = 0; f < NF_; ++f)
                a = fmaf(pwcl[g * 40 + f], dwo[f * 100 + tp * 4 + dt], a);
            sum += elu_f(a);
        }
        po[e] = sum * 0.25f;
    }
    __syncthreads();
    for (int e = tid; e < 400; e += 256) {
        const int tp = e >> 4;
        const int k = e & 15;
        float a = bpl[k];
        for (int g = 0; g < 80; ++g)
            a = fmaf(WPl[k * 80 + g], po[g * 25 + tp], a);
        xp[(b * TP_ + tp0 + tp) * K_ + k] = a;
    }
}

// Scan via readlane broadcast (round-0 verified structure): 16 blocks
// (1 batch each), 1 wave. 32 independent v_readlane ops broadcast h0
// (row 2) and h1 (row 0) into SGPRs. Upper half computes
// h0_{i+1} = tanh(LN(M0*h0_i + x_{i+1})); lower half computes
// h1_i = tanh(LN(wx1*h0_i + M1*h1_{i-1} + b1)) in the SAME iteration.
// Round-5 trims: exp2 fold (2*log2e absorbed into LN gain/bias, removing
// a multiply from the serial tanh chain) and 4-way fma accumulator split
// (chain depth 8 -> 4).
#define SCAN_STEP(I, S) do {                                              \
    float sH0[16], sH1[16];                                               \
    _Pragma("unroll")                                                     \
    for (int j = 0; j < 16; ++j) {                                        \
        sH0[j] = RDLANE(vA, 32 + j);                                      \
        sH1[j] = RDLANE(vA, j);                                           \
    }                                                                     \
    float a0 = 0.f, a1 = 0.f, a2 = 0.f, a3 = 0.f;                         \
    float c0 = 0.f, c1 = 0.f, c2 = 0.f, c3 = 0.f;                         \
    _Pragma("unroll")                                                     \
    for (int j = 0; j < 16; j += 4) {                                     \
        a0 = fmaf(WA[j],     sH0[j],     a0);                             \
        a1 = fmaf(WA[j + 1], sH0[j + 1], a1);                             \
        a2 = fmaf(WA[j + 2], sH0[j + 2], a2);                             \
        a3 = fmaf(WA[j + 3], sH0[j + 3], a3);                             \
        c0 = fmaf(WB[j],     sH1[j],     c0);                             \
        c1 = fmaf(WB[j + 1], sH1[j + 1], c1);                             \
        c2 = fmaf(WB[j + 2], sH1[j + 2], c2);                             \
        c3 = fmaf(WB[j + 3], sH1[j + 3], c3);                             \
    }                                                                     \
    const float xv = xn[S];                                               \
    int tf = (I) + 5; if (tf > TP_ - 1) tf = TP_ - 1;                     \
    xn[S] = xpb[tf * K_];                                                 \
    const float cadd = lower ? b1r : xv;                                  \
    const float pre = (((a0 + a1) + (a2 + a3)) +                          \
                       ((c0 + c1) + (c2 + c3))) + cadd;                   \
    float s1 = pre, s2 = pre * pre;                                       \
    RSUM16(s1);                                                           \
    RSUM16(s2);                                                           \
    const float mu = s1 * 0.0625f;                                        \
    const float var = fmaf(s2, 0.0625f, -mu * mu);                        \
    vA = tanh2e_f(fmaf((pre - mu) * rsqrtf(var + 1e-5f), gg, bb));        \
} while (0)

__global__ __launch_bounds__(64, 1) void k3_scan(
    const float* __restrict__ xp, const float* __restrict__ M0,
    const float* __restrict__ M1, const float* __restrict__ wx1,
    const float* __restrict__ b1, const float* __restrict__ ln0_g,
    const float* __restrict__ ln0_b, const float* __restrict__ ln1_g,
    const float* __restrict__ ln1_b, float* __restrict__ out) {
    const int lane = threadIdx.x;
    const int k = lane & 15;
    const bool lower = lane < 32;
    const int b = blockIdx.x;

    // direct-indexed weights: sH0[j]/sH1[j] carry exact element j, so no
    // permutation is needed (readlane formulation is layout-exact).
    float WA[16], WB[16];
#pragma unroll
    for (int j = 0; j < 16; ++j) {
        const float m0 = M0[k * 16 + j];
        const float m1 = M1[k * 16 + j];
        const float wx = wx1[k * 16 + j];
        WA[j] = lower ? wx : m0;   // coefficient on h0
        WB[j] = lower ? m1 : 0.f;  // coefficient on h1
    }
    const float b1r = b1[k];
    const float g0 = C2F * ln0_g[k], be0 = C2F * ln0_b[k];
    const float gg = lower ? C2F * ln1_g[k] : g0;
    const float bb = lower ? C2F * ln1_b[k] : be0;
    const float* xpb = xp + b * TP_ * K_ + k;

    // prologue: h0_0 = tanh(LN(x_0)) computed by all lanes
    float h0_0;
    {
        const float x0 = xpb[0];
        float s1 = x0, s2 = x0 * x0;
        RSUM16(s1);
        RSUM16(s2);
        const float mu = s1 * 0.0625f;
        const float var = fmaf(s2, 0.0625f, -mu * mu);
        h0_0 = tanh2e_f(fmaf((x0 - mu) * rsqrtf(var + 1e-5f), g0, be0));
    }
    // vA: upper = h0 state (h0_0), lower = h1 state (h1_{-1} = 0)
    float vA = lower ? 0.f : h0_0;

    float xn[4];
    xn[0] = xpb[1 * K_];
    xn[1] = xpb[2 * K_];
    xn[2] = xpb[3 * K_];
    xn[3] = xpb[4 * K_];

    // iter i (0..499): upper -> h0_{i+1}; lower -> h1_i (uses h0_i, h1_{i-1})
    for (int i = 0; i < TP_; i += 4) {
        SCAN_STEP(i + 0, 0);
        SCAN_STEP(i + 1, 1);
        SCAN_STEP(i + 2, 2);
        SCAN_STEP(i + 3, 3);
    }
    if (lane < 16) {
        out[b * K_ + k] = vA;               // Z = h1_{499} (row 0 state)
        if (k == 0) out[256 + b] = 1.0f;    // alpha = softmax over size-1 axis
    }
}

extern "C" void kernel_launch(void* const* d_in, const int* in_sizes, int n_in,
                              void* d_out, int out_size, void* d_ws, size_t ws_size,
                              hipStream_t stream) {
    const float* x       = (const float*)d_in[0];
    const float* dw_w    = (const float*)d_in[13];
    const float* dw_b    = (const float*)d_in[14];
    const float* wx1     = (const float*)d_in[29];
    const float* b1      = (const float*)d_in[32];
    const float* ln0_g   = (const float*)d_in[27];
    const float* ln0_b   = (const float*)d_in[28];
    const float* ln1_g   = (const float*)d_in[33];
    const float* ln1_b   = (const float*)d_in[34];
    float* ws = (float*)d_ws;
    float* out = (float*)d_out;

    P0 p;
    p.tconv_w = (const float*)d_in[1]; p.tconv_b = (const float*)d_in[2];
    p.tbn_g = (const float*)d_in[3]; p.tbn_b = (const float*)d_in[4];
    p.tbn_m = (const float*)d_in[5]; p.tbn_v = (const float*)d_in[6];
    p.sconv_b = (const float*)d_in[8];
    p.sbn_g = (const float*)d_in[9]; p.sbn_b = (const float*)d_in[10];
    p.sbn_m = (const float*)d_in[11]; p.sbn_v = (const float*)d_in[12];
    p.pw_w = (const float*)d_in[15]; p.pw_b = (const float*)d_in[16];
    p.pbn_g = (const float*)d_in[17]; p.pbn_b = (const float*)d_in[18];
    p.pbn_m = (const float*)d_in[19]; p.pbn_v = (const float*)d_in[20];
    p.proj_w = (const float*)d_in[21]; p.proj_b = (const float*)d_in[22];
    p.wx0 = (const float*)d_in[23]; p.b0 = (const float*)d_in[26];
    p.L0 = (const float*)d_in[24]; p.ll0 = (const float*)d_in[25];
    p.L1 = (const float*)d_in[30]; p.ll1 = (const float*)d_in[31];
    p.sconv_w = (const float*)d_in[7];
    p.ws = ws;

    unsigned short* w2b = (unsigned short*)(ws + OFF_W2U);
    unsigned short* w1a = (unsigned short*)(ws + OFF_W1A);

    k0_all<<<dim3(1452), dim3(256), 0, stream>>>(p);
    k1_mfma<<<dim3(1024), dim3(256), 0, stream>>>(x, w1a, w2b, ws + OFF_S2R);
    k2_dwpw<<<dim3(320), dim3(256), 0, stream>>>(ws + OFF_S2R, ws + OFF_SB2,
                                                 dw_w, dw_b, ws + OFF_PWC,
                                                 ws + OFF_PB2, ws + OFF_WP, ws + OFF_BP,
                                                 ws + OFF_XP);
    k3_scan<<<dim3(16), dim3(64), 0, stream>>>(ws + OFF_XP, ws + OFF_M0, ws + OFF_M1,
                                               wx1, b1, ln0_g, ln0_b, ln1_g, ln1_b, out);
}